// Round 7
// baseline (137.654 us; speedup 1.0000x reference)
//
#include <hip/hip_runtime.h>
#include <cfloat>
#include <stdint.h>

// KmeansVectorQuantizer: B=8, T=2048, G=8, D=64, V=1024
// Outputs (flat f32): ids[B*T*G], quantized_st[B*T*G*D], kmeans, commit, total
#define G_ 8
#define D_ 64
#define V_ 1024
#define BT_ 16384
#define TPB_ 256              // vq_scan: 4 waves
#define PREPB_ 256            // prep block size
#define NSLOT_ 128            // spread loss-accumulator slots
#define TOKS_ 64              // tokens per scan block
#define NC_ 64                // codewords per chunk
#define NB_ 2                 // LDS chunk buffers
#define NCHUNK_ (V_ / NC_)    // 16 chunks

typedef unsigned long long u64;
typedef uint32_t u32;
typedef _Float16 h8 __attribute__((ext_vector_type(8)));
typedef _Float16 h4 __attribute__((ext_vector_type(4)));
typedef float f32x4 __attribute__((ext_vector_type(4)));

typedef __attribute__((address_space(3))) uint32_t lds_u32;
typedef __attribute__((address_space(1))) uint32_t glb_u32;

// global->LDS DMA, 16B per lane; LDS dest = wave-uniform base + lane*16
#define GL2LDS(gsrc, ldst) \
    __builtin_amdgcn_global_load_lds((glb_u32*)(gsrc), (lds_u32*)(ldst), 16, 0, 0)

// ws layout (bytes):
//   [0..511]     float part[128]        loss partial slots (memset 0)
//   [512..515]   int   cnt_active       (memset 0)
//   [1024)       float csqT[G_*V_]      32 KB  (transposed [g][v])
//   [33792)      int   list[BT_]        64 KB
//   [131072)     f16   cbH[V_*G_*64]    1 MB   codebook hi  (natural [v][g][d])
//   [1179648)    f16   cbL[V_*G_*64]    1 MB   codebook (lo*2^12)

// Fused prep: csq transpose, f32->f16 hi/lo codebook split, block-aggregated
// active compaction (1 atomic/block), coalesced zero-fill of padded tokens.
__global__ void prep_csq(const float* __restrict__ cb, const int* __restrict__ pad,
                         float* __restrict__ csqT,
                         int* __restrict__ cnt, int* __restrict__ list,
                         float* __restrict__ out_ids, float* __restrict__ out_q,
                         _Float16* __restrict__ cbH, _Float16* __restrict__ cbL) {
    const int tid = threadIdx.x;
    const int idx = blockIdx.x * PREPB_ + tid;   // < BT_ (exact grid)

    if (idx < V_ * G_) {
        const float4* r = (const float4*)(cb + (size_t)idx * D_);
        _Float16* hp = cbH + (size_t)idx * 64;
        _Float16* lp = cbL + (size_t)idx * 64;
        float s = 0.f;
#pragma unroll
        for (int i = 0; i < D_ / 4; ++i) {
            float4 c = r[i];
            s += c.x * c.x + c.y * c.y + c.z * c.z + c.w * c.w;
            float xs[4] = {c.x, c.y, c.z, c.w};
            h4 hv, lv;
#pragma unroll
            for (int e = 0; e < 4; ++e) {
                _Float16 hh = (_Float16)xs[e];
                hv[e] = hh;
                lv[e] = (_Float16)((xs[e] - (float)hh) * 4096.f);
            }
            *(h4*)(hp + i * 4) = hv;
            *(h4*)(lp + i * 4) = lv;
        }
        csqT[(idx & (G_ - 1)) * V_ + (idx >> 3)] = s;
    }

    __shared__ int s_cnt[8];          // [0..3] active per wave, [4..7] padded
    __shared__ int s_base, s_npl;
    __shared__ int s_plist[PREPB_];   // block-local padded tokens
    const int lane = tid & 63, w = tid >> 6;
    const bool active = (pad[idx] == 0);
    u64 bal = __ballot(active);
    int na  = __popcll(bal);
    if (lane == 0) { s_cnt[w] = na; s_cnt[4 + w] = 64 - na; }
    __syncthreads();
    if (tid == 0) {
        int ta = s_cnt[0] + s_cnt[1] + s_cnt[2] + s_cnt[3];
        s_base = atomicAdd(cnt, ta);
        s_npl  = PREPB_ - ta;
    }
    __syncthreads();
    int pre_a = 0, pre_p = 0;
    for (int i = 0; i < w; ++i) { pre_a += s_cnt[i]; pre_p += s_cnt[4 + i]; }
    const u64 mb = ((u64)1 << lane) - 1;
    if (active) list[s_base + pre_a + __popcll(bal & mb)] = idx;
    else        s_plist[pre_p + __popcll(~bal & mb)] = idx;
    __syncthreads();

    // coalesced zero-fill: one wave per padded token (2 KB contiguous)
    const int npl = s_npl;
    for (int i = w; i < npl; i += 4) {
        int tok = s_plist[i];
        float4 z = make_float4(0.f, 0.f, 0.f, 0.f);
        float4* q = (float4*)(out_q + (size_t)tok * (G_ * D_)) + lane * 2;
        q[0] = z;
        q[1] = z;
        if (lane < G_) out_ids[(size_t)tok * G_ + lane] = -1.0f;
    }
}

// MFMA scan, occupancy-doubled frame: block = 64 tok x 1024 cw (one g),
// 4 waves (mh x nh; wave = 32 tok x 32 cols/chunk, rf=2). LDS = 2 x 64-cw
// chunk buffers (H+L) + csq + merge = 37.9 KB -> 4 blocks/CU = 16 waves/CU
// (2x R6's TLP), ~1024 working blocks = exactly capacity. Pipeline: wait
// {vmcnt(0); s_barrier} at iteration TOP (waits only chunk c, issued one
// full iteration earlier -> latency covered by iter c-1 compute), THEN
// issue c+1, then compute c -- just-issued loads never waited in-loop.
// fp32 emulated as f16 hi/lo (lo pre-scaled 2^12); cq folded into the hh
// accumulator seed; fold = argmax of e = a + 2^-12*ac. XOR-swizzled LDS via
// inverse-swizzled global source (read-side ^((row&7)<<4); 0 conflicts).
__global__ __launch_bounds__(TPB_, 4) void vq_scan(
    const float* __restrict__ inp,
    const float* __restrict__ cb,
    const float* __restrict__ csqT,
    const int* __restrict__ cnt,
    const int* __restrict__ list,
    const _Float16* __restrict__ cbH,
    const _Float16* __restrict__ cbL,
    float* __restrict__ out_ids,
    float* __restrict__ out_q,
    float* __restrict__ part) {

    __shared__ __align__(16) unsigned char BH[NB_][NC_ * 128]; // 16 KB f16 hi
    __shared__ __align__(16) unsigned char BL[NB_][NC_ * 128]; // 16 KB f16 lo
    __shared__ float csq_s[V_];                                //  4 KB
    __shared__ u64 merge_s[2][TOKS_];                          //  1 KB

    const int nact = cnt[0];
    const int tile = blockIdx.x;
    if (tile * TOKS_ >= nact) return;          // uniform early-exit (pre-barrier)
    const int g    = blockIdx.y;
    const int tid  = threadIdx.x;
    const int lane = tid & 63;
    const int w    = tid >> 6;          // 0..3
    const int mh   = w >> 1;            // token half  (0..1)
    const int nh   = w & 1;             // column half (0..1)
    const int r16  = lane & 15;
    const int kq   = lane >> 4;

    // ---- A fragments FIRST (their waitcnts then don't drain the DMA queue) --
    h8 AH[2][2], AL[2][2];
#pragma unroll
    for (int rf = 0; rf < 2; ++rf) {
        int p = tile * TOKS_ + mh * 32 + rf * 16 + r16;
        int tok = list[p < nact ? p : 0];
        const float* xr = inp + (size_t)tok * (G_ * D_) + g * D_;
#pragma unroll
        for (int kf = 0; kf < 2; ++kf) {
            const float4* xp = (const float4*)(xr + kf * 32 + kq * 8);
            float4 a = xp[0], b = xp[1];
            float xs[8] = {a.x, a.y, a.z, a.w, b.x, b.y, b.z, b.w};
#pragma unroll
            for (int e = 0; e < 8; ++e) {
                _Float16 hh = (_Float16)xs[e];
                AH[rf][kf][e] = hh;
                AL[rf][kf][e] = (_Float16)((xs[e] - (float)hh) * 4096.f);
            }
        }
    }

    // per-lane DMA source: wave slice = rows w*16..w*16+15 of the 64-row chunk;
    // LDS linear L = w*2048 + i*1024 + lane*16 -> row = w*16+i*8+(lane>>3),
    // blk = lane&7; inverse-swizzle source block so LDS[row][blk] =
    // logical[row][blk ^ (row&7)]   (row&7 == lane>>3 here)
    const size_t soff = (size_t)(w * 16 + (lane >> 3)) * 1024
                      + (size_t)g * 128
                      + (size_t)(((lane & 7) ^ (lane >> 3)) * 16);
    const unsigned char* sH = (const unsigned char*)cbH + soff;
    const unsigned char* sL = (const unsigned char*)cbL + soff;
    const int ldsb = w * 2048;

    // ---- prologue: issue chunk 0 (4 loads/wave) ----
    GL2LDS(sH,        &BH[0][ldsb]);
    GL2LDS(sH + 8192, &BH[0][ldsb + 1024]);
    GL2LDS(sL,        &BL[0][ldsb]);
    GL2LDS(sL + 8192, &BL[0][ldsb + 1024]);

    csq_s[tid]       = csqT[g * V_ + tid];
    csq_s[tid + 256] = csqT[g * V_ + tid + 256];
    csq_s[tid + 512] = csqT[g * V_ + tid + 512];
    csq_s[tid + 768] = csqT[g * V_ + tid + 768];

    float beste[8];
    int   bestid[8];
#pragma unroll
    for (int s = 0; s < 8; ++s) { beste[s] = -FLT_MAX / 2; bestid[s] = 0; }

    // csq_s ds_writes must be complete before the first barrier
    asm volatile("s_waitcnt lgkmcnt(0)" ::: "memory");

    // b-frag logical byte = col*128 + kq*16 (col = nh*32 + cf*16 + r16),
    // swizzle ^((col&7)<<4) = ^((r16&7)<<4); kfrag flips bit 6 post-swizzle
    const u32 o0 = (u32)((((nh * 32 + r16) * 128 + kq * 16))
                         ^ ((u32)(r16 & 7) << 4));

#pragma unroll 1
    for (int c = 0; c < NCHUNK_; ++c) {
        // fused wait+barrier at iteration top: waits ONLY chunk c (issued one
        // iteration ago; latency already covered), then barrier. No memory op
        // may slip between (single asm). Chunk c+1 is issued after -> its
        // loads are never waited inside the loop.
        asm volatile("s_waitcnt vmcnt(0)\n\ts_barrier" ::: "memory");
        __builtin_amdgcn_sched_barrier(0);

        if (c + 1 < NCHUNK_) {             // prefetch next chunk (post-barrier:
            const int b = (c + 1) & 1;     // target buffer's readers are done)
            const size_t adv = (size_t)(c + 1) * 65536;
            GL2LDS(sH + adv,        &BH[b][ldsb]);
            GL2LDS(sH + adv + 8192, &BH[b][ldsb + 1024]);
            GL2LDS(sL + adv,        &BL[b][ldsb]);
            GL2LDS(sL + adv + 8192, &BL[b][ldsb + 1024]);
        }

        const unsigned char* BHc = &BH[c & 1][0];
        const unsigned char* BLc = &BL[c & 1][0];
#pragma unroll
        for (int cf = 0; cf < 2; ++cf) {
            const u32 ob = o0 + (u32)(cf * 2048);
            const h8 bh0 = *(const h8*)(BHc + ob);
            const h8 bh1 = *(const h8*)(BHc + (ob ^ 64));
            const h8 bl0 = *(const h8*)(BLc + ob);
            const h8 bl1 = *(const h8*)(BLc + (ob ^ 64));
            const int vcol = c * NC_ + nh * 32 + cf * 16 + r16;
            const float ai = -0.5f * csq_s[vcol];
#pragma unroll
            for (int rf = 0; rf < 2; ++rf) {
                f32x4 a  = {ai, ai, ai, ai};
                f32x4 ac = {0.f, 0.f, 0.f, 0.f};
                a  = __builtin_amdgcn_mfma_f32_16x16x32_f16(AH[rf][0], bh0, a,  0, 0, 0);
                a  = __builtin_amdgcn_mfma_f32_16x16x32_f16(AH[rf][1], bh1, a,  0, 0, 0);
                ac = __builtin_amdgcn_mfma_f32_16x16x32_f16(AH[rf][0], bl0, ac, 0, 0, 0);
                ac = __builtin_amdgcn_mfma_f32_16x16x32_f16(AH[rf][1], bl1, ac, 0, 0, 0);
                ac = __builtin_amdgcn_mfma_f32_16x16x32_f16(AL[rf][0], bh0, ac, 0, 0, 0);
                ac = __builtin_amdgcn_mfma_f32_16x16x32_f16(AL[rf][1], bh1, ac, 0, 0, 0);
#pragma unroll
                for (int q = 0; q < 4; ++q) {
                    // e = -d/2 exactly; argmax e == argmin d, ties -> first
                    float e = fmaf(0x1.0p-12f, ac[q], a[q]);
                    int s = rf * 4 + q;
                    if (e > beste[s]) { beste[s] = e; bestid[s] = vcol; }
                }
            }
        }
    }

    // ---- cross-lane argmin (16-lane butterfly) + cross-nh merge ----
#pragma unroll
    for (int s = 0; s < 8; ++s) {
        float d = -2.f * beste[s];
        u32 u = __float_as_uint(d);
        u = u ^ ((u >> 31) ? 0xFFFFFFFFu : 0x80000000u);   // sortable float
        u64 pk = ((u64)u << 32) | (u32)bestid[s];
#pragma unroll
        for (int off = 1; off <= 8; off <<= 1) {
            u64 o = __shfl_xor(pk, off, 64);
            pk = (o < pk) ? o : pk;
        }
        if (r16 == 0) {
            int row = mh * 32 + (s >> 2) * 16 + kq * 4 + (s & 3);
            merge_s[nh][row] = pk;
        }
    }
    __syncthreads();

    // ---- fused epilogue: ids, quantized, loss (4 threads per token) ----
    float l = 0.f;
    {
        int tl = tid >> 2, qv = tid & 3;       // tl 0..63
        int p  = tile * TOKS_ + tl;
        if (p < nact) {
            int tok = list[p];
            u64 qa = merge_s[0][tl], qb = merge_s[1][tl];
            u64 qm = (qb < qa) ? qb : qa;
            int id  = (int)(qm & 0xFFFFFFFFull);
            const float4* cr = (const float4*)(cb + ((size_t)id * G_ + g) * D_) + qv * 4;
            const float4* xr = (const float4*)(inp + (size_t)tok * (G_ * D_) + g * D_) + qv * 4;
            float4* qo = (float4*)(out_q + (size_t)tok * (G_ * D_) + g * D_) + qv * 4;
#pragma unroll
            for (int k = 0; k < 4; ++k) {
                float4 cc = cr[k], xx = xr[k];
                float dx = cc.x - xx.x, dy = cc.y - xx.y;
                float dz = cc.z - xx.z, dw = cc.w - xx.w;
                l += dx * dx + dy * dy + dz * dz + dw * dw;
                qo[k] = cc;
            }
            if (qv == 0) out_ids[(size_t)tok * G_ + g] = (float)id;
        }
    }
#pragma unroll
    for (int off = 32; off > 0; off >>= 1) l += __shfl_down(l, off, 64);
    if (lane == 0) {
        int slot = ((blockIdx.y * gridDim.x + blockIdx.x) * 4 + w) & (NSLOT_ - 1);
        atomicAdd(&part[slot], l);
    }
}

__global__ void finalize_kernel(const float* __restrict__ part,
                                const int* __restrict__ cnt,
                                float* __restrict__ out_losses) {
    int lane = threadIdx.x;                    // one wave of 64
    float l = part[lane] + part[lane + 64];
#pragma unroll
    for (int off = 32; off > 0; off >>= 1) l += __shfl_down(l, off, 64);
    if (lane == 0) {
        float k = l / (float)cnt[0];
        out_losses[0] = k;        // kmeans_loss
        out_losses[1] = k;        // commitment_loss (numerically identical)
        out_losses[2] = 2.f * k;  // total (BETA=1)
    }
}

extern "C" void kernel_launch(void* const* d_in, const int* in_sizes, int n_in,
                              void* d_out, int out_size, void* d_ws, size_t ws_size,
                              hipStream_t stream) {
    const float* inp = (const float*)d_in[0];   // (8,2048,512) f32
    const int*   pad = (const int*)d_in[1];     // (8,2048) i32
    const float* cb  = (const float*)d_in[2];   // (1024,8,64) f32

    float* out   = (float*)d_out;
    float* o_ids = out;                              // B*T*G
    float* o_q   = out + (size_t)BT_ * G_;           // B*T*G*D
    float* o_ls  = o_q + (size_t)BT_ * G_ * D_;      // 3 scalars

    float*     part = (float*)d_ws;
    int*       cnt  = (int*)((char*)d_ws + 512);
    float*     csqT = (float*)((char*)d_ws + 1024);
    int*       list = (int*)((char*)d_ws + 33792);
    _Float16*  cbH  = (_Float16*)((char*)d_ws + 131072);
    _Float16*  cbL  = (_Float16*)((char*)d_ws + 131072 + 1048576);

    hipMemsetAsync(d_ws, 0, 1024, stream);

    prep_csq<<<dim3(BT_ / PREPB_), dim3(PREPB_), 0, stream>>>(
        cb, pad, csqT, cnt, list, o_ids, o_q, cbH, cbL);

    dim3 grid(BT_ / TOKS_, G_);                // worst-case 64-token tiles x g
    vq_scan<<<grid, dim3(TPB_), 0, stream>>>(
        inp, cb, csqT, cnt, list, cbH, cbL, o_ids, o_q, part);

    finalize_kernel<<<1, dim3(64), 0, stream>>>(part, cnt, o_ls);
}

// Round 8
// 129.905 us; speedup vs baseline: 1.0597x; 1.0597x over previous
//
#include <hip/hip_runtime.h>
#include <cfloat>
#include <stdint.h>

// KmeansVectorQuantizer: B=8, T=2048, G=8, D=64, V=1024
// Outputs (flat f32): ids[B*T*G], quantized_st[B*T*G*D], kmeans, commit, total
#define G_ 8
#define D_ 64
#define V_ 1024
#define BT_ 16384
#define TPB_ 256              // vq_scan: 4 waves
#define NSLOT_ 128            // spread loss-accumulator slots
#define TOKS_ 128             // tokens per scan block
#define NC_ 64                // codewords per chunk
#define NB_ 4                 // LDS chunk buffers (3-deep prefetch)
#define NCHUNK_ (V_ / NC_)    // 16 chunks

typedef unsigned long long u64;
typedef uint32_t u32;
typedef _Float16 h8 __attribute__((ext_vector_type(8)));
typedef float f32x4 __attribute__((ext_vector_type(4)));

typedef __attribute__((address_space(3))) uint32_t lds_u32;
typedef __attribute__((address_space(1))) uint32_t glb_u32;

// global->LDS DMA, 16B per lane; LDS dest = wave-uniform base + lane*16
#define GL2LDS(gsrc, ldst) \
    __builtin_amdgcn_global_load_lds((glb_u32*)(gsrc), (lds_u32*)(ldst), 16, 0, 0)

// ws layout (bytes):
//   [0..511]     float part[128]        loss partial slots (memset 0)
//   [512..515]   int   cnt_active       (memset 0)
//   [1024)       float csqT[G_*V_]      32 KB  (transposed [g][v])
//   [33792)      int   list[BT_]        64 KB
//   [131072)     f16   cbH[V_*G_*64]    1 MB   codebook hi  (natural [v][g][d])
//   [1179648)    f16   cbL[V_*G_*64]    1 MB   codebook (lo*2^12)

// Full-device prep: 256 blocks x 256 thr (65,536 threads; was 8,192).
// Phase A: one thread per 8 codebook elems -- coalesced f32x8 load, f16 hi/lo
//          convert, csq row-sum via 3-step shfl_xor over the row's 8 lanes.
// Phase B: each block compacts its 64 tokens (wave 0: ballot + 1 atomicAdd;
//          list order is irrelevant -- outputs are indexed by token).
// Phase C: coalesced zero-fill of padded tokens, 256x more blocks than before.
__global__ __launch_bounds__(256) void prep_csq(
        const float* __restrict__ cb, const int* __restrict__ pad,
        float* __restrict__ csqT,
        int* __restrict__ cnt, int* __restrict__ list,
        float* __restrict__ out_ids, float* __restrict__ out_q,
        _Float16* __restrict__ cbH, _Float16* __restrict__ cbL) {
    const int tid = threadIdx.x;
    const int bx  = blockIdx.x;              // 0..255
    const int lane = tid & 63, w = tid >> 6;

    // ---- Phase A: codebook convert + csq ----
    {
        const int gid = bx * 256 + tid;      // 0..65535
        const int row = gid >> 3;            // (v,g) row, 0..8191
        const int seg = gid & 7;             // 8-elem segment within row
        const float4* r = (const float4*)(cb + (size_t)row * 64 + seg * 8);
        float4 c0 = r[0], c1 = r[1];
        float xs[8] = {c0.x, c0.y, c0.z, c0.w, c1.x, c1.y, c1.z, c1.w};
        h8 hv, lv;
        float s = 0.f;
#pragma unroll
        for (int e = 0; e < 8; ++e) {
            s += xs[e] * xs[e];
            _Float16 hh = (_Float16)xs[e];
            hv[e] = hh;
            lv[e] = (_Float16)((xs[e] - (float)hh) * 4096.f);
        }
        *(h8*)(cbH + (size_t)row * 64 + seg * 8) = hv;
        *(h8*)(cbL + (size_t)row * 64 + seg * 8) = lv;
        s += __shfl_xor(s, 1, 64);           // row's 8 lanes are consecutive
        s += __shfl_xor(s, 2, 64);
        s += __shfl_xor(s, 4, 64);
        if (seg == 0) csqT[(row & (G_ - 1)) * V_ + (row >> 3)] = s;
    }

    // ---- Phase B: compaction of this block's 64 tokens (wave 0) ----
    __shared__ int s_plist[64];
    __shared__ int s_npl;
    if (w == 0) {
        int tok = bx * 64 + lane;
        bool active = (pad[tok] == 0);
        u64 bal = __ballot(active);
        int na  = __popcll(bal);
        int base = 0;
        if (lane == 0) base = atomicAdd(cnt, na);
        base = __shfl(base, 0, 64);
        const u64 mb = ((u64)1 << lane) - 1;
        if (active) list[base + __popcll(bal & mb)] = tok;
        else        s_plist[__popcll(~bal & mb)] = tok;
        if (lane == 0) s_npl = 64 - na;
    }
    __syncthreads();

    // ---- Phase C: zero-fill padded tokens (2 KB per wave-iter, coalesced) --
    const int npl = s_npl;
    for (int i = w; i < npl; i += 4) {
        int tok = s_plist[i];
        float4 z = make_float4(0.f, 0.f, 0.f, 0.f);
        float4* q = (float4*)(out_q + (size_t)tok * (G_ * D_)) + lane * 2;
        q[0] = z;
        q[1] = z;
        if (lane < G_) out_ids[(size_t)tok * G_ + lane] = -1.0f;
    }
}

// MFMA scan, R6 frame (best measured: 43.4 us) -- unchanged this round.
// block = 128 tok x 1024 cw (one g), 4 waves (mh x nh); chunks of 64 cw in
// 4 LDS buffers, DMA'd 3 ahead via global_load_lds. Per chunk iteration:
// single asm {s_waitcnt vmcnt(8); s_barrier} (oldest chunk landed; 2 newer
// stay in flight -- never drain to 0 in the loop), then issue chunk c+3,
// then compute. fp32 emulated as f16 hi/lo (lo pre-scaled 2^12); cq folded
// into the hh accumulator seed; fold = argmax of e = a + 2^-12*ac.
// XOR-swizzled LDS via inverse-swizzled global source (0 conflicts).
__global__ __launch_bounds__(TPB_, 2) void vq_scan(
    const float* __restrict__ inp,
    const float* __restrict__ cb,
    const float* __restrict__ csqT,
    const int* __restrict__ cnt,
    const int* __restrict__ list,
    const _Float16* __restrict__ cbH,
    const _Float16* __restrict__ cbL,
    float* __restrict__ out_ids,
    float* __restrict__ out_q,
    float* __restrict__ part) {

    __shared__ __align__(16) unsigned char BH[NB_][NC_ * 128]; // 32 KB f16 hi
    __shared__ __align__(16) unsigned char BL[NB_][NC_ * 128]; // 32 KB f16 lo
    __shared__ float csq_s[V_];                                //  4 KB
    __shared__ u64 merge_s[2][TOKS_];                          //  2 KB

    const int nact = cnt[0];
    const int tile = blockIdx.x;
    if (tile * TOKS_ >= nact) return;          // uniform early-exit (pre-barrier)
    const int g    = blockIdx.y;
    const int tid  = threadIdx.x;
    const int lane = tid & 63;
    const int w    = tid >> 6;          // 0..3
    const int mh   = w >> 1;            // token half  (0..1)
    const int nh   = w & 1;             // column half (0..1)
    const int r16  = lane & 15;
    const int kq   = lane >> 4;

    // ---- A fragments FIRST (their waitcnts then don't drain the DMA queue) --
    h8 AH[4][2], AL[4][2];
#pragma unroll
    for (int rf = 0; rf < 4; ++rf) {
        int p = tile * TOKS_ + mh * 64 + rf * 16 + r16;
        int tok = list[p < nact ? p : 0];
        const float* xr = inp + (size_t)tok * (G_ * D_) + g * D_;
#pragma unroll
        for (int kf = 0; kf < 2; ++kf) {
            const float4* xp = (const float4*)(xr + kf * 32 + kq * 8);
            float4 a = xp[0], b = xp[1];
            float xs[8] = {a.x, a.y, a.z, a.w, b.x, b.y, b.z, b.w};
#pragma unroll
            for (int e = 0; e < 8; ++e) {
                _Float16 hh = (_Float16)xs[e];
                AH[rf][kf][e] = hh;
                AL[rf][kf][e] = (_Float16)((xs[e] - (float)hh) * 4096.f);
            }
        }
    }

    // per-lane DMA source: wave slice = rows w*16..w*16+15 of the 64-row chunk;
    // LDS linear L = w*2048 + i*1024 + lane*16 -> row = w*16+i*8+(lane>>3),
    // blk = lane&7; inverse-swizzle source block so LDS[row][blk] =
    // logical[row][blk ^ (row&7)]   (row&7 == lane>>3 here)
    const size_t soff = (size_t)(w * 16 + (lane >> 3)) * 1024
                      + (size_t)g * 128
                      + (size_t)(((lane & 7) ^ (lane >> 3)) * 16);
    const unsigned char* sH = (const unsigned char*)cbH + soff;
    const unsigned char* sL = (const unsigned char*)cbL + soff;
    const int ldsb = w * 2048;

    // ---- prologue: issue chunks 0,1,2 (12 loads/wave in flight) ----
#pragma unroll
    for (int c0 = 0; c0 < 3; ++c0) {
        const size_t adv = (size_t)c0 * 65536;   // 64 rows * 1024 B
        GL2LDS(sH + adv,        &BH[c0][ldsb]);
        GL2LDS(sH + adv + 8192, &BH[c0][ldsb + 1024]);
        GL2LDS(sL + adv,        &BL[c0][ldsb]);
        GL2LDS(sL + adv + 8192, &BL[c0][ldsb + 1024]);
    }

    csq_s[tid]       = csqT[g * V_ + tid];
    csq_s[tid + 256] = csqT[g * V_ + tid + 256];
    csq_s[tid + 512] = csqT[g * V_ + tid + 512];
    csq_s[tid + 768] = csqT[g * V_ + tid + 768];

    float beste[16];
    int   bestid[16];
#pragma unroll
    for (int s = 0; s < 16; ++s) { beste[s] = -FLT_MAX / 2; bestid[s] = 0; }

    // csq_s ds_writes must be complete before the first barrier
    asm volatile("s_waitcnt lgkmcnt(0)" ::: "memory");

    // b-frag logical byte = col*128 + kq*16 (col = nh*32 + cf*16 + r16),
    // swizzle ^((col&7)<<4) = ^((r16&7)<<4); kfrag flips bit 6 post-swizzle
    const u32 o0 = (u32)((((nh * 32 + r16) * 128 + kq * 16))
                         ^ ((u32)(r16 & 7) << 4));

#pragma unroll 1
    for (int c = 0; c < NCHUNK_; ++c) {
        // fused counted-wait + barrier: no memory op may cross (single asm).
        // vmcnt(8): 2 newest chunks may stay in flight; chunk c is landed.
        if (c < NCHUNK_ - 2)
            asm volatile("s_waitcnt vmcnt(8)\n\ts_barrier" ::: "memory");
        else if (c == NCHUNK_ - 2)
            asm volatile("s_waitcnt vmcnt(4)\n\ts_barrier" ::: "memory");
        else
            asm volatile("s_waitcnt vmcnt(0)\n\ts_barrier" ::: "memory");
        __builtin_amdgcn_sched_barrier(0);

        if (c + 3 < NCHUNK_) {             // prefetch 3 ahead (post-barrier:
            const int b = (c + 3) & (NB_ - 1);   // target buffer's readers done)
            const size_t adv = (size_t)(c + 3) * 65536;
            GL2LDS(sH + adv,        &BH[b][ldsb]);
            GL2LDS(sH + adv + 8192, &BH[b][ldsb + 1024]);
            GL2LDS(sL + adv,        &BL[b][ldsb]);
            GL2LDS(sL + adv + 8192, &BL[b][ldsb + 1024]);
        }

        const unsigned char* BHc = &BH[c & (NB_ - 1)][0];
        const unsigned char* BLc = &BL[c & (NB_ - 1)][0];
#pragma unroll
        for (int cf = 0; cf < 2; ++cf) {
            const u32 ob = o0 + (u32)(cf * 2048);
            const h8 bh0 = *(const h8*)(BHc + ob);
            const h8 bh1 = *(const h8*)(BHc + (ob ^ 64));
            const h8 bl0 = *(const h8*)(BLc + ob);
            const h8 bl1 = *(const h8*)(BLc + (ob ^ 64));
            const int vcol = c * NC_ + nh * 32 + cf * 16 + r16;
            const float ai = -0.5f * csq_s[vcol];
#pragma unroll
            for (int rf = 0; rf < 4; ++rf) {
                f32x4 a  = {ai, ai, ai, ai};
                f32x4 ac = {0.f, 0.f, 0.f, 0.f};
                a  = __builtin_amdgcn_mfma_f32_16x16x32_f16(AH[rf][0], bh0, a,  0, 0, 0);
                a  = __builtin_amdgcn_mfma_f32_16x16x32_f16(AH[rf][1], bh1, a,  0, 0, 0);
                ac = __builtin_amdgcn_mfma_f32_16x16x32_f16(AH[rf][0], bl0, ac, 0, 0, 0);
                ac = __builtin_amdgcn_mfma_f32_16x16x32_f16(AH[rf][1], bl1, ac, 0, 0, 0);
                ac = __builtin_amdgcn_mfma_f32_16x16x32_f16(AL[rf][0], bh0, ac, 0, 0, 0);
                ac = __builtin_amdgcn_mfma_f32_16x16x32_f16(AL[rf][1], bh1, ac, 0, 0, 0);
#pragma unroll
                for (int q = 0; q < 4; ++q) {
                    // e = -d/2 exactly; argmax e == argmin d, ties -> first
                    float e = fmaf(0x1.0p-12f, ac[q], a[q]);
                    int s = rf * 4 + q;
                    if (e > beste[s]) { beste[s] = e; bestid[s] = vcol; }
                }
            }
        }
    }

    // ---- cross-lane argmin (16-lane butterfly) + cross-nh merge ----
#pragma unroll
    for (int s = 0; s < 16; ++s) {
        float d = -2.f * beste[s];
        u32 u = __float_as_uint(d);
        u = u ^ ((u >> 31) ? 0xFFFFFFFFu : 0x80000000u);   // sortable float
        u64 pk = ((u64)u << 32) | (u32)bestid[s];
#pragma unroll
        for (int off = 1; off <= 8; off <<= 1) {
            u64 o = __shfl_xor(pk, off, 64);
            pk = (o < pk) ? o : pk;
        }
        if (r16 == 0) {
            int row = mh * 64 + (s >> 2) * 16 + kq * 4 + (s & 3);
            merge_s[nh][row] = pk;
        }
    }
    __syncthreads();

    // ---- fused epilogue: ids, quantized, loss (2 threads per token) ----
    float l = 0.f;
    {
        int tl = tid >> 1, qv = tid & 1;
        int p  = tile * TOKS_ + tl;
        if (p < nact) {
            int tok = list[p];
            u64 qa = merge_s[0][tl], qb = merge_s[1][tl];
            u64 qm = (qb < qa) ? qb : qa;
            int id  = (int)(qm & 0xFFFFFFFFull);
            const float4* cr = (const float4*)(cb + ((size_t)id * G_ + g) * D_) + qv * 8;
            const float4* xr = (const float4*)(inp + (size_t)tok * (G_ * D_) + g * D_) + qv * 8;
            float4* qo = (float4*)(out_q + (size_t)tok * (G_ * D_) + g * D_) + qv * 8;
#pragma unroll
            for (int k = 0; k < 8; ++k) {
                float4 cc = cr[k], xx = xr[k];
                float dx = cc.x - xx.x, dy = cc.y - xx.y;
                float dz = cc.z - xx.z, dw = cc.w - xx.w;
                l += dx * dx + dy * dy + dz * dz + dw * dw;
                qo[k] = cc;
            }
            if (qv == 0) out_ids[(size_t)tok * G_ + g] = (float)id;
        }
    }
#pragma unroll
    for (int off = 32; off > 0; off >>= 1) l += __shfl_down(l, off, 64);
    if (lane == 0) {
        int slot = ((blockIdx.y * gridDim.x + blockIdx.x) * 4 + w) & (NSLOT_ - 1);
        atomicAdd(&part[slot], l);
    }
}

__global__ void finalize_kernel(const float* __restrict__ part,
                                const int* __restrict__ cnt,
                                float* __restrict__ out_losses) {
    int lane = threadIdx.x;                    // one wave of 64
    float l = part[lane] + part[lane + 64];
#pragma unroll
    for (int off = 32; off > 0; off >>= 1) l += __shfl_down(l, off, 64);
    if (lane == 0) {
        float k = l / (float)cnt[0];
        out_losses[0] = k;        // kmeans_loss
        out_losses[1] = k;        // commitment_loss (numerically identical)
        out_losses[2] = 2.f * k;  // total (BETA=1)
    }
}

extern "C" void kernel_launch(void* const* d_in, const int* in_sizes, int n_in,
                              void* d_out, int out_size, void* d_ws, size_t ws_size,
                              hipStream_t stream) {
    const float* inp = (const float*)d_in[0];   // (8,2048,512) f32
    const int*   pad = (const int*)d_in[1];     // (8,2048) i32
    const float* cb  = (const float*)d_in[2];   // (1024,8,64) f32

    float* out   = (float*)d_out;
    float* o_ids = out;                              // B*T*G
    float* o_q   = out + (size_t)BT_ * G_;           // B*T*G*D
    float* o_ls  = o_q + (size_t)BT_ * G_ * D_;      // 3 scalars

    float*     part = (float*)d_ws;
    int*       cnt  = (int*)((char*)d_ws + 512);
    float*     csqT = (float*)((char*)d_ws + 1024);
    int*       list = (int*)((char*)d_ws + 33792);
    _Float16*  cbH  = (_Float16*)((char*)d_ws + 131072);
    _Float16*  cbL  = (_Float16*)((char*)d_ws + 131072 + 1048576);

    hipMemsetAsync(d_ws, 0, 1024, stream);

    prep_csq<<<dim3(256), dim3(256), 0, stream>>>(
        cb, pad, csqT, cnt, list, o_ids, o_q, cbH, cbL);

    dim3 grid(BT_ / TOKS_, G_);                // worst-case 128-token tiles x g
    vq_scan<<<grid, dim3(TPB_), 0, stream>>>(
        inp, cb, csqT, cnt, list, cbH, cbL, o_ids, o_q, part);

    finalize_kernel<<<1, dim3(64), 0, stream>>>(part, cnt, o_ls);
}

// Round 9
// 128.251 us; speedup vs baseline: 1.0733x; 1.0129x over previous
//
#include <hip/hip_runtime.h>
#include <cfloat>
#include <stdint.h>

// KmeansVectorQuantizer: B=8, T=2048, G=8, D=64, V=1024
// Outputs (flat f32): ids[B*T*G], quantized_st[B*T*G*D], kmeans, commit, total
#define G_ 8
#define D_ 64
#define V_ 1024
#define BT_ 16384
#define TPB_ 256              // vq_scan: 4 waves
#define NSLOT_ 128            // spread loss-accumulator slots
#define TOKS_ 128             // tokens per scan block
#define NC_ 64                // codewords per chunk
#define NB_ 4                 // LDS chunk buffers (3-deep prefetch)
#define NCHUNK_ (V_ / NC_)    // 16 chunks

typedef unsigned long long u64;
typedef uint32_t u32;
typedef _Float16 h8 __attribute__((ext_vector_type(8)));
typedef float f32x4 __attribute__((ext_vector_type(4)));

typedef __attribute__((address_space(3))) uint32_t lds_u32;
typedef __attribute__((address_space(1))) uint32_t glb_u32;

// global->LDS DMA, 16B per lane; LDS dest = wave-uniform base + lane*16
#define GL2LDS(gsrc, ldst) \
    __builtin_amdgcn_global_load_lds((glb_u32*)(gsrc), (lds_u32*)(ldst), 16, 0, 0)

// ws layout (bytes):
//   [0..511]     float part[128]        loss partial slots (memset 0)
//   [512..515]   int   cnt_active       (memset 0)
//   [1024)       float csqT[G_*V_]      32 KB  (transposed [g][v])
//   [33792)      int   list[BT_]        64 KB
//   [131072)     f16   cbH[G_*V_*64]    1 MB   codebook hi  -- GROUP-MAJOR [g][v][d]
//   [1179648)    f16   cbL[G_*V_*64]    1 MB   codebook lo*2^12 -- [g][v][d]
//
// GROUP-MAJOR is the R9 change: a scan block (fixed g) stages 64 consecutive
// 128B rows = 8KB contiguous per chunk. The old [v][g][d] layout made every
// global_load_lds a 1KB-strided gather touching 64 cache lines for 1KB of
// data -- ~8x L2 over-fetch (~1 GB/kernel through L2 = the measured wall).

// Full-device prep: 256 blocks x 256 thr.
// Phase A: one thread per 8 codebook elems -- coalesced f32x8 load, f16 hi/lo
//          convert (stored group-major), csq row-sum via 3-step shfl_xor.
// Phase B: each block compacts its 64 tokens (wave 0: ballot + 1 atomicAdd;
//          list order is irrelevant -- outputs are indexed by token).
// Phase C: coalesced zero-fill of padded tokens.
__global__ __launch_bounds__(256) void prep_csq(
        const float* __restrict__ cb, const int* __restrict__ pad,
        float* __restrict__ csqT,
        int* __restrict__ cnt, int* __restrict__ list,
        float* __restrict__ out_ids, float* __restrict__ out_q,
        _Float16* __restrict__ cbH, _Float16* __restrict__ cbL) {
    const int tid = threadIdx.x;
    const int bx  = blockIdx.x;              // 0..255
    const int lane = tid & 63, w = tid >> 6;

    // ---- Phase A: codebook convert + csq (group-major store) ----
    {
        const int gid = bx * 256 + tid;      // 0..65535
        const int row = gid >> 3;            // (v,g) row, 0..8191  (= v*8+g)
        const int seg = gid & 7;             // 8-elem segment within row
        const int v   = row >> 3, gg = row & 7;
        const float4* r = (const float4*)(cb + (size_t)row * 64 + seg * 8);
        float4 c0 = r[0], c1 = r[1];
        float xs[8] = {c0.x, c0.y, c0.z, c0.w, c1.x, c1.y, c1.z, c1.w};
        h8 hv, lv;
        float s = 0.f;
#pragma unroll
        for (int e = 0; e < 8; ++e) {
            s += xs[e] * xs[e];
            _Float16 hh = (_Float16)xs[e];
            hv[e] = hh;
            lv[e] = (_Float16)((xs[e] - (float)hh) * 4096.f);
        }
        const size_t dst = ((size_t)gg * V_ + v) * 64 + seg * 8;
        *(h8*)(cbH + dst) = hv;
        *(h8*)(cbL + dst) = lv;
        s += __shfl_xor(s, 1, 64);           // row's 8 lanes are consecutive
        s += __shfl_xor(s, 2, 64);
        s += __shfl_xor(s, 4, 64);
        if (seg == 0) csqT[gg * V_ + v] = s;
    }

    // ---- Phase B: compaction of this block's 64 tokens (wave 0) ----
    __shared__ int s_plist[64];
    __shared__ int s_npl;
    if (w == 0) {
        int tok = bx * 64 + lane;
        bool active = (pad[tok] == 0);
        u64 bal = __ballot(active);
        int na  = __popcll(bal);
        int base = 0;
        if (lane == 0) base = atomicAdd(cnt, na);
        base = __shfl(base, 0, 64);
        const u64 mb = ((u64)1 << lane) - 1;
        if (active) list[base + __popcll(bal & mb)] = tok;
        else        s_plist[__popcll(~bal & mb)] = tok;
        if (lane == 0) s_npl = 64 - na;
    }
    __syncthreads();

    // ---- Phase C: zero-fill padded tokens (2 KB per wave-iter, coalesced) --
    const int npl = s_npl;
    for (int i = w; i < npl; i += 4) {
        int tok = s_plist[i];
        float4 z = make_float4(0.f, 0.f, 0.f, 0.f);
        float4* q = (float4*)(out_q + (size_t)tok * (G_ * D_)) + lane * 2;
        q[0] = z;
        q[1] = z;
        if (lane < G_) out_ids[(size_t)tok * G_ + lane] = -1.0f;
    }
}

// MFMA scan, R6/R8 frame; R9 changes ONLY the DMA source addressing (group-
// major codebook -> fully coalesced 1KB-per-instruction staging; the XOR
// swizzle permutes 16B blocks within each 128B line, so coalescing holds).
// LDS image is byte-identical to R8 -> all downstream math & ids bit-exact.
// block = 128 tok x 1024 cw (one g), 4 waves (mh x nh); chunks of 64 cw in
// 4 LDS buffers, DMA'd 3 ahead via global_load_lds; per-iter fused
// {s_waitcnt vmcnt(8); s_barrier} (never drain to 0 in-loop). fp32 emulated
// as f16 hi/lo (lo pre-scaled 2^12); cq folded into the hh accumulator seed;
// fold = argmax of e = a + 2^-12*ac.
__global__ __launch_bounds__(TPB_, 2) void vq_scan(
    const float* __restrict__ inp,
    const float* __restrict__ cb,
    const float* __restrict__ csqT,
    const int* __restrict__ cnt,
    const int* __restrict__ list,
    const _Float16* __restrict__ cbH,
    const _Float16* __restrict__ cbL,
    float* __restrict__ out_ids,
    float* __restrict__ out_q,
    float* __restrict__ part) {

    __shared__ __align__(16) unsigned char BH[NB_][NC_ * 128]; // 32 KB f16 hi
    __shared__ __align__(16) unsigned char BL[NB_][NC_ * 128]; // 32 KB f16 lo
    __shared__ float csq_s[V_];                                //  4 KB
    __shared__ u64 merge_s[2][TOKS_];                          //  2 KB

    const int nact = cnt[0];
    const int tile = blockIdx.x;
    if (tile * TOKS_ >= nact) return;          // uniform early-exit (pre-barrier)
    const int g    = blockIdx.y;
    const int tid  = threadIdx.x;
    const int lane = tid & 63;
    const int w    = tid >> 6;          // 0..3
    const int mh   = w >> 1;            // token half  (0..1)
    const int nh   = w & 1;             // column half (0..1)
    const int r16  = lane & 15;
    const int kq   = lane >> 4;

    // ---- A fragments FIRST (their waitcnts then don't drain the DMA queue) --
    h8 AH[4][2], AL[4][2];
#pragma unroll
    for (int rf = 0; rf < 4; ++rf) {
        int p = tile * TOKS_ + mh * 64 + rf * 16 + r16;
        int tok = list[p < nact ? p : 0];
        const float* xr = inp + (size_t)tok * (G_ * D_) + g * D_;
#pragma unroll
        for (int kf = 0; kf < 2; ++kf) {
            const float4* xp = (const float4*)(xr + kf * 32 + kq * 8);
            float4 a = xp[0], b = xp[1];
            float xs[8] = {a.x, a.y, a.z, a.w, b.x, b.y, b.z, b.w};
#pragma unroll
            for (int e = 0; e < 8; ++e) {
                _Float16 hh = (_Float16)xs[e];
                AH[rf][kf][e] = hh;
                AL[rf][kf][e] = (_Float16)((xs[e] - (float)hh) * 4096.f);
            }
        }
    }

    // per-lane DMA source (group-major): chunk c of group g = 64 consecutive
    // 128B rows at cbH + g*131072 + c*8192. LDS linear L = w*2048 + i*1024 +
    // lane*16 -> row r = w*16 + i*8 + (lane>>3), blk = lane&7; inverse-swizzle
    // the source 16B block so LDS[r][blk] = logical[r][blk ^ (r&7)]
    // (r&7 == lane>>3 here). Lanes 0..7 span one 128B line -> coalesced.
    const size_t soff = (size_t)(w * 16 + (lane >> 3)) * 128
                      + (size_t)(((lane & 7) ^ (lane >> 3)) * 16);
    const unsigned char* sH = (const unsigned char*)cbH + (size_t)g * 131072 + soff;
    const unsigned char* sL = (const unsigned char*)cbL + (size_t)g * 131072 + soff;
    const int ldsb = w * 2048;

    // ---- prologue: issue chunks 0,1,2 (12 loads/wave in flight) ----
#pragma unroll
    for (int c0 = 0; c0 < 3; ++c0) {
        const size_t adv = (size_t)c0 * 8192;    // 64 rows * 128 B
        GL2LDS(sH + adv,        &BH[c0][ldsb]);
        GL2LDS(sH + adv + 1024, &BH[c0][ldsb + 1024]);
        GL2LDS(sL + adv,        &BL[c0][ldsb]);
        GL2LDS(sL + adv + 1024, &BL[c0][ldsb + 1024]);
    }

    csq_s[tid]       = csqT[g * V_ + tid];
    csq_s[tid + 256] = csqT[g * V_ + tid + 256];
    csq_s[tid + 512] = csqT[g * V_ + tid + 512];
    csq_s[tid + 768] = csqT[g * V_ + tid + 768];

    float beste[16];
    int   bestid[16];
#pragma unroll
    for (int s = 0; s < 16; ++s) { beste[s] = -FLT_MAX / 2; bestid[s] = 0; }

    // csq_s ds_writes must be complete before the first barrier
    asm volatile("s_waitcnt lgkmcnt(0)" ::: "memory");

    // b-frag logical byte = col*128 + kq*16 (col = nh*32 + cf*16 + r16),
    // swizzle ^((col&7)<<4) = ^((r16&7)<<4); kfrag flips bit 6 post-swizzle
    const u32 o0 = (u32)((((nh * 32 + r16) * 128 + kq * 16))
                         ^ ((u32)(r16 & 7) << 4));

#pragma unroll 1
    for (int c = 0; c < NCHUNK_; ++c) {
        // fused counted-wait + barrier: no memory op may cross (single asm).
        // vmcnt(8): 2 newest chunks may stay in flight; chunk c is landed.
        if (c < NCHUNK_ - 2)
            asm volatile("s_waitcnt vmcnt(8)\n\ts_barrier" ::: "memory");
        else if (c == NCHUNK_ - 2)
            asm volatile("s_waitcnt vmcnt(4)\n\ts_barrier" ::: "memory");
        else
            asm volatile("s_waitcnt vmcnt(0)\n\ts_barrier" ::: "memory");
        __builtin_amdgcn_sched_barrier(0);

        if (c + 3 < NCHUNK_) {             // prefetch 3 ahead (post-barrier:
            const int b = (c + 3) & (NB_ - 1);   // target buffer's readers done)
            const size_t adv = (size_t)(c + 3) * 8192;
            GL2LDS(sH + adv,        &BH[b][ldsb]);
            GL2LDS(sH + adv + 1024, &BH[b][ldsb + 1024]);
            GL2LDS(sL + adv,        &BL[b][ldsb]);
            GL2LDS(sL + adv + 1024, &BL[b][ldsb + 1024]);
        }

        const unsigned char* BHc = &BH[c & (NB_ - 1)][0];
        const unsigned char* BLc = &BL[c & (NB_ - 1)][0];
#pragma unroll
        for (int cf = 0; cf < 2; ++cf) {
            const u32 ob = o0 + (u32)(cf * 2048);
            const h8 bh0 = *(const h8*)(BHc + ob);
            const h8 bh1 = *(const h8*)(BHc + (ob ^ 64));
            const h8 bl0 = *(const h8*)(BLc + ob);
            const h8 bl1 = *(const h8*)(BLc + (ob ^ 64));
            const int vcol = c * NC_ + nh * 32 + cf * 16 + r16;
            const float ai = -0.5f * csq_s[vcol];
#pragma unroll
            for (int rf = 0; rf < 4; ++rf) {
                f32x4 a  = {ai, ai, ai, ai};
                f32x4 ac = {0.f, 0.f, 0.f, 0.f};
                a  = __builtin_amdgcn_mfma_f32_16x16x32_f16(AH[rf][0], bh0, a,  0, 0, 0);
                a  = __builtin_amdgcn_mfma_f32_16x16x32_f16(AH[rf][1], bh1, a,  0, 0, 0);
                ac = __builtin_amdgcn_mfma_f32_16x16x32_f16(AH[rf][0], bl0, ac, 0, 0, 0);
                ac = __builtin_amdgcn_mfma_f32_16x16x32_f16(AH[rf][1], bl1, ac, 0, 0, 0);
                ac = __builtin_amdgcn_mfma_f32_16x16x32_f16(AL[rf][0], bh0, ac, 0, 0, 0);
                ac = __builtin_amdgcn_mfma_f32_16x16x32_f16(AL[rf][1], bh1, ac, 0, 0, 0);
#pragma unroll
                for (int q = 0; q < 4; ++q) {
                    // e = -d/2 exactly; argmax e == argmin d, ties -> first
                    float e = fmaf(0x1.0p-12f, ac[q], a[q]);
                    int s = rf * 4 + q;
                    if (e > beste[s]) { beste[s] = e; bestid[s] = vcol; }
                }
            }
        }
    }

    // ---- cross-lane argmin (16-lane butterfly) + cross-nh merge ----
#pragma unroll
    for (int s = 0; s < 16; ++s) {
        float d = -2.f * beste[s];
        u32 u = __float_as_uint(d);
        u = u ^ ((u >> 31) ? 0xFFFFFFFFu : 0x80000000u);   // sortable float
        u64 pk = ((u64)u << 32) | (u32)bestid[s];
#pragma unroll
        for (int off = 1; off <= 8; off <<= 1) {
            u64 o = __shfl_xor(pk, off, 64);
            pk = (o < pk) ? o : pk;
        }
        if (r16 == 0) {
            int row = mh * 64 + (s >> 2) * 16 + kq * 4 + (s & 3);
            merge_s[nh][row] = pk;
        }
    }
    __syncthreads();

    // ---- fused epilogue: ids, quantized, loss (2 threads per token) ----
    float l = 0.f;
    {
        int tl = tid >> 1, qv = tid & 1;
        int p  = tile * TOKS_ + tl;
        if (p < nact) {
            int tok = list[p];
            u64 qa = merge_s[0][tl], qb = merge_s[1][tl];
            u64 qm = (qb < qa) ? qb : qa;
            int id  = (int)(qm & 0xFFFFFFFFull);
            const float4* cr = (const float4*)(cb + ((size_t)id * G_ + g) * D_) + qv * 8;
            const float4* xr = (const float4*)(inp + (size_t)tok * (G_ * D_) + g * D_) + qv * 8;
            float4* qo = (float4*)(out_q + (size_t)tok * (G_ * D_) + g * D_) + qv * 8;
#pragma unroll
            for (int k = 0; k < 8; ++k) {
                float4 cc = cr[k], xx = xr[k];
                float dx = cc.x - xx.x, dy = cc.y - xx.y;
                float dz = cc.z - xx.z, dw = cc.w - xx.w;
                l += dx * dx + dy * dy + dz * dz + dw * dw;
                qo[k] = cc;
            }
            if (qv == 0) out_ids[(size_t)tok * G_ + g] = (float)id;
        }
    }
#pragma unroll
    for (int off = 32; off > 0; off >>= 1) l += __shfl_down(l, off, 64);
    if (lane == 0) {
        int slot = ((blockIdx.y * gridDim.x + blockIdx.x) * 4 + w) & (NSLOT_ - 1);
        atomicAdd(&part[slot], l);
    }
}

__global__ void finalize_kernel(const float* __restrict__ part,
                                const int* __restrict__ cnt,
                                float* __restrict__ out_losses) {
    int lane = threadIdx.x;                    // one wave of 64
    float l = part[lane] + part[lane + 64];
#pragma unroll
    for (int off = 32; off > 0; off >>= 1) l += __shfl_down(l, off, 64);
    if (lane == 0) {
        float k = l / (float)cnt[0];
        out_losses[0] = k;        // kmeans_loss
        out_losses[1] = k;        // commitment_loss (numerically identical)
        out_losses[2] = 2.f * k;  // total (BETA=1)
    }
}

extern "C" void kernel_launch(void* const* d_in, const int* in_sizes, int n_in,
                              void* d_out, int out_size, void* d_ws, size_t ws_size,
                              hipStream_t stream) {
    const float* inp = (const float*)d_in[0];   // (8,2048,512) f32
    const int*   pad = (const int*)d_in[1];     // (8,2048) i32
    const float* cb  = (const float*)d_in[2];   // (1024,8,64) f32

    float* out   = (float*)d_out;
    float* o_ids = out;                              // B*T*G
    float* o_q   = out + (size_t)BT_ * G_;           // B*T*G*D
    float* o_ls  = o_q + (size_t)BT_ * G_ * D_;      // 3 scalars

    float*     part = (float*)d_ws;
    int*       cnt  = (int*)((char*)d_ws + 512);
    float*     csqT = (float*)((char*)d_ws + 1024);
    int*       list = (int*)((char*)d_ws + 33792);
    _Float16*  cbH  = (_Float16*)((char*)d_ws + 131072);
    _Float16*  cbL  = (_Float16*)((char*)d_ws + 131072 + 1048576);

    hipMemsetAsync(d_ws, 0, 1024, stream);

    prep_csq<<<dim3(256), dim3(256), 0, stream>>>(
        cb, pad, csqT, cnt, list, o_ids, o_q, cbH, cbL);

    dim3 grid(BT_ / TOKS_, G_);                // worst-case 128-token tiles x g
    vq_scan<<<grid, dim3(TPB_), 0, stream>>>(
        inp, cb, csqT, cnt, list, cbH, cbL, o_ids, o_q, part);

    finalize_kernel<<<1, dim3(64), 0, stream>>>(part, cnt, o_ls);
}